// Round 3
// baseline (4547.572 us; speedup 1.0000x reference)
//
#include <hip/hip_runtime.h>

constexpr int SL  = 384;
constexpr int N2  = SL * SL;      // 147456
constexpr int CH  = 64;
constexpr int D1  = 788;
constexpr int D2  = 210;
constexpr float EPSF = 1e-5f;

__device__ __forceinline__ float lrelu(float v){ return v >= 0.f ? v : 0.01f * v; }

__device__ __forceinline__ float wred(float v){
  #pragma unroll
  for (int o = 32; o; o >>= 1) v += __shfl_down(v, o, 64);
  return v;
}

// ---------------- per-channel stats (sum, sumsq) over n elements ----------------
__global__ void stats_k(const float* __restrict__ x, int n, float* __restrict__ part){
  const int c = blockIdx.y, s = blockIdx.x, S = gridDim.x;
  const int chunk = (n + S - 1) / S;
  const int st = s * chunk;
  const int en = min(n, st + chunk);
  const float* p = x + (size_t)c * n;
  float sm = 0.f, ss = 0.f;
  for (int i = st + threadIdx.x; i < en; i += blockDim.x){
    float v = p[i]; sm += v; ss += v * v;
  }
  sm = wred(sm); ss = wred(ss);
  __shared__ float aux[8];
  const int wid = threadIdx.x >> 6, lane = threadIdx.x & 63;
  if (lane == 0){ aux[wid] = sm; aux[4 + wid] = ss; }
  __syncthreads();
  if (threadIdx.x == 0){
    part[((size_t)c * S + s) * 2]     = aux[0] + aux[1] + aux[2] + aux[3];
    part[((size_t)c * S + s) * 2 + 1] = aux[4] + aux[5] + aux[6] + aux[7];
  }
}

__global__ void stats_final_k(const float* __restrict__ part, int C, int S, float ninv,
                              float* __restrict__ mean, float* __restrict__ rstd){
  const int c = blockIdx.x * blockDim.x + threadIdx.x;
  if (c >= C) return;
  float sm = 0.f, ss = 0.f;
  for (int s = 0; s < S; ++s){ sm += part[(c * S + s) * 2]; ss += part[(c * S + s) * 2 + 1]; }
  const float m = sm * ninv;
  const float v = ss * ninv - m * m;
  mean[c] = m;
  rstd[c] = rsqrtf(v + EPSF);
}

// ---------------- 1d branch ----------------
// x1's mean cancels in pair1's inorm (constant per output channel); apply rstd only.
__global__ void rowcol_k(const float* __restrict__ x1d, const float* __restrict__ W1,
                         const float* __restrict__ r1,
                         float* __restrict__ row, float* __restrict__ col){
  const int idx = blockIdx.x * 256 + threadIdx.x;      // 0 .. 2*64*384-1
  const int half = idx / (CH * SL);
  const int rem  = idx % (CH * SL);
  const int c = rem / SL, l = rem % SL;
  const float* wp = W1 + (size_t)c * (2 * D1) + (size_t)half * D1;  // wave-uniform
  float acc = 0.f;
  for (int d = 0; d < D1; ++d)
    acc += wp[d] * (x1d[(size_t)d * SL + l] * r1[d]);
  (half ? col : row)[c * SL + l] = acc;
}

// Var(row_i + col_j) = Var(row)+Var(col); mean = mean(row)+mean(col)  (exact)
__global__ void rowcol_stats_k(const float* __restrict__ row, const float* __restrict__ col,
                               float* __restrict__ m1, float* __restrict__ rs1){
  const int c = blockIdx.x;
  float sr = 0, ssr = 0, sc = 0, ssc = 0;
  for (int i = threadIdx.x; i < SL; i += blockDim.x){
    float r = row[c * SL + i]; sr += r; ssr += r * r;
    float q = col[c * SL + i]; sc += q; ssc += q * q;
  }
  sr = wred(sr); ssr = wred(ssr); sc = wred(sc); ssc = wred(ssc);
  __shared__ float aux[16];
  const int wid = threadIdx.x >> 6, lane = threadIdx.x & 63;
  if (lane == 0){ aux[wid] = sr; aux[4+wid] = ssr; aux[8+wid] = sc; aux[12+wid] = ssc; }
  __syncthreads();
  if (threadIdx.x == 0){
    float a = 0, b = 0, d = 0, e = 0;
    for (int i = 0; i < 4; ++i){ a += aux[i]; b += aux[4+i]; d += aux[8+i]; e += aux[12+i]; }
    const float mr = a / SL, mc = d / SL;
    const float vr = b / SL - mr * mr, vc = e / SL - mc * mc;
    m1[c]  = mr + mc;
    rs1[c] = rsqrtf(vr + vc + EPSF);
  }
}

__global__ void pair1n_k(const float* __restrict__ row, const float* __restrict__ col,
                         const float* __restrict__ m1, const float* __restrict__ rs1,
                         const float* __restrict__ g1, const float* __restrict__ b1,
                         float* __restrict__ out){
  const int c = blockIdx.y;
  const int p = blockIdx.x * 256 + threadIdx.x;
  const float a  = rs1[c] * g1[c];
  const float bb = b1[c] - m1[c] * a;
  const float v = row[c * SL + p / SL] + col[c * SL + p % SL];
  out[(size_t)c * N2 + p] = lrelu(v * a + bb);
}

// ---------------- 2d branch: x2 rstd folds into W2 (x2 mean cancels in pair2 inorm) ----
__global__ void w2eff_k(const float* __restrict__ W2, const float* __restrict__ r2,
                        float* __restrict__ w2e){
  const int c = threadIdx.x;
  if (c >= CH) return;
  for (int d = 0; d < D2; ++d)
    w2e[d * CH + c] = W2[(size_t)c * D2 + d] * r2[d];   // transposed [d][c]
}

__global__ __launch_bounds__(256) void gemm_pair2_k(const float* __restrict__ x2,
                                                    const float* __restrict__ w2e,
                                                    float* __restrict__ out){
  const int p = blockIdx.x * 256 + threadIdx.x;
  float acc[CH];
  #pragma unroll
  for (int c = 0; c < CH; ++c) acc[c] = 0.f;
  for (int d = 0; d < D2; ++d){
    const float xv = x2[(size_t)d * N2 + p];
    const float4* w4 = (const float4*)(w2e + d * CH);   // wave-uniform -> scalar loads
    #pragma unroll
    for (int q = 0; q < CH / 4; ++q){
      float4 w = w4[q];
      acc[4*q] += w.x*xv; acc[4*q+1] += w.y*xv; acc[4*q+2] += w.z*xv; acc[4*q+3] += w.w*xv;
    }
  }
  #pragma unroll
  for (int c = 0; c < CH; ++c)
    out[(size_t)c * N2 + p] = acc[c];
}

__global__ void w3t_k(const float* __restrict__ W3, float* __restrict__ w3t){
  const int i = blockIdx.x * 256 + threadIdx.x;
  if (i >= CH * 2 * CH) return;
  const int c = i / (2 * CH), e = i % (2 * CH);
  w3t[e * CH + c] = W3[i];
}

__global__ __launch_bounds__(256) void gemm_mix_k(const float* __restrict__ A,
                                                  const float* __restrict__ B,
                                                  const float* __restrict__ w3t,
                                                  float* __restrict__ out){
  const int p = blockIdx.x * 256 + threadIdx.x;
  float acc[CH];
  #pragma unroll
  for (int c = 0; c < CH; ++c) acc[c] = 0.f;
  for (int e = 0; e < CH; ++e){
    const float xv = A[(size_t)e * N2 + p];
    const float4* w4 = (const float4*)(w3t + e * CH);
    #pragma unroll
    for (int q = 0; q < CH / 4; ++q){
      float4 w = w4[q];
      acc[4*q] += w.x*xv; acc[4*q+1] += w.y*xv; acc[4*q+2] += w.z*xv; acc[4*q+3] += w.w*xv;
    }
  }
  for (int e = 0; e < CH; ++e){
    const float xv = B[(size_t)e * N2 + p];
    const float4* w4 = (const float4*)(w3t + (CH + e) * CH);
    #pragma unroll
    for (int q = 0; q < CH / 4; ++q){
      float4 w = w4[q];
      acc[4*q] += w.x*xv; acc[4*q+1] += w.y*xv; acc[4*q+2] += w.z*xv; acc[4*q+3] += w.w*xv;
    }
  }
  #pragma unroll
  for (int c = 0; c < CH; ++c)
    out[(size_t)c * N2 + p] = acc[c];
}

// ---------------- inorm-affine + leaky (+ optional residual add) ----------------
__global__ void normleaky_k(const float* __restrict__ src, float* __restrict__ dst,
                            const float* __restrict__ mean, const float* __restrict__ rstd,
                            const float* __restrict__ g, const float* __restrict__ be,
                            int goff, const float* __restrict__ res){
  const int c = blockIdx.y;
  const int p = blockIdx.x * 256 + threadIdx.x;
  const size_t idx = (size_t)c * N2 + p;
  const float a  = rstd[c] * g[goff + c];
  const float bb = be[goff + c] - mean[c] * a;
  float v = lrelu(src[idx] * a + bb);
  if (res) v += res[idx];
  dst[idx] = v;
}

// conv weights [conv][oc][ic][3][3] -> [conv][ic][tap][oc]  (conv bias cancels in inorm)
__global__ void wt_k(const float* __restrict__ w, float* __restrict__ wt){
  const int i = blockIdx.x * 256 + threadIdx.x;
  if (i >= 10 * CH * CH * 9) return;
  const int oc  = i % CH;
  const int tap = (i / CH) % 9;
  const int ic  = (i / (CH * 9)) % CH;
  const int cv  = i / (CH * 9 * CH);
  wt[i] = w[((size_t)(cv * CH + oc) * CH + ic) * 9 + tap];
}

// ---------------- dilated 3x3 conv, thread = 1 pixel x 16 oc ----------------
template<int DIL>
__global__ __launch_bounds__(256) void conv_k(const float* __restrict__ in,
                                              const float* __restrict__ wt,
                                              float* __restrict__ out){
  const int p = blockIdx.x * 256 + threadIdx.x;
  const int ocg = blockIdx.y;                       // 0..3 -> 16 oc each
  const int y = p / SL, x = p % SL;
  float acc[16];
  #pragma unroll
  for (int o = 0; o < 16; ++o) acc[o] = 0.f;
  for (int ic = 0; ic < CH; ++ic){
    const float* ip = in + (size_t)ic * N2;
    const float* wb = wt + (ic * 9) * CH + ocg * 16;   // wave-uniform -> scalar loads
    #pragma unroll
    for (int ky = 0; ky < 3; ++ky){
      const int yy = y + (ky - 1) * DIL;
      const bool yok = (unsigned)yy < (unsigned)SL;
      #pragma unroll
      for (int kx = 0; kx < 3; ++kx){
        const int xx = x + (kx - 1) * DIL;
        const float xv = (yok && ((unsigned)xx < (unsigned)SL)) ? ip[yy * SL + xx] : 0.f;
        const float4* w4 = (const float4*)(wb + (ky * 3 + kx) * CH);
        float4 w0 = w4[0], w1 = w4[1], w2 = w4[2], w3 = w4[3];
        acc[0]  += w0.x*xv; acc[1]  += w0.y*xv; acc[2]  += w0.z*xv; acc[3]  += w0.w*xv;
        acc[4]  += w1.x*xv; acc[5]  += w1.y*xv; acc[6]  += w1.z*xv; acc[7]  += w1.w*xv;
        acc[8]  += w2.x*xv; acc[9]  += w2.y*xv; acc[10] += w2.z*xv; acc[11] += w2.w*xv;
        acc[12] += w3.x*xv; acc[13] += w3.y*xv; acc[14] += w3.z*xv; acc[15] += w3.w*xv;
      }
    }
  }
  #pragma unroll
  for (int o = 0; o < 16; ++o)
    out[(size_t)(ocg * 16 + o) * N2 + p] = acc[o];
}

static void launch_conv(int dil, const float* src, const float* wtl, float* dst, hipStream_t s){
  dim3 g(N2 / 256, 4);
  switch (dil){
    case 1:  conv_k<1><<<g, 256, 0, s>>>(src, wtl, dst); break;
    case 2:  conv_k<2><<<g, 256, 0, s>>>(src, wtl, dst); break;
    default: conv_k<4><<<g, 256, 0, s>>>(src, wtl, dst); break;
  }
}

extern "C" void kernel_launch(void* const* d_in, const int* in_sizes, int n_in,
                              void* d_out, int out_size, void* d_ws, size_t ws_size,
                              hipStream_t stream){
  const float* x1d    = (const float*)d_in[0];
  const float* x2     = (const float*)d_in[1];
  const float* W1     = (const float*)d_in[2];
  const float* g1     = (const float*)d_in[3];
  const float* b1     = (const float*)d_in[4];
  const float* W2     = (const float*)d_in[5];
  // g2/b2 at 6/7, W3 at 8, g3/b3 at 9/10
  const float* res_w  = (const float*)d_in[11];
  // d_in[12] = res_b: cancels exactly in the following instance-norm
  const float* res_g  = (const float*)d_in[13];
  const float* res_be = (const float*)d_in[14];
  float* X = (float*)d_out;          // residual stream lives in d_out (fp32)

  float* ws = (float*)d_ws;
  float* A    = ws; ws += (size_t)CH * N2;     // 37.75 MB
  float* Bb   = ws; ws += (size_t)CH * N2;     // 37.75 MB
  float* row  = ws; ws += CH * SL;
  float* col  = ws; ws += CH * SL;
  float* s1m  = ws; ws += D1;   float* s1r  = ws; ws += D1;
  float* s2m  = ws; ws += 256;  float* s2r  = ws; ws += 256;
  float* m1   = ws; ws += 64;   float* rs1  = ws; ws += 64;
  float* smv  = ws; ws += 64;   float* srv  = ws; ws += 64;
  float* w2e  = ws; ws += D2 * CH;
  float* w3t  = ws; ws += 2 * CH * CH;
  float* wt   = ws; ws += 10 * CH * CH * 9;
  float* part = ws; ws += 32768;               // total ~77.4 MB (R1 proved this fits)

  // ---- 1d branch
  stats_k<<<dim3(1, D1), 256, 0, stream>>>(x1d, SL, part);
  stats_final_k<<<(D1 + 255) / 256, 256, 0, stream>>>(part, D1, 1, 1.f / SL, s1m, s1r);
  rowcol_k<<<2 * CH * SL / 256, 256, 0, stream>>>(x1d, W1, s1r, row, col);
  rowcol_stats_k<<<CH, 256, 0, stream>>>(row, col, m1, rs1);
  pair1n_k<<<dim3(N2 / 256, CH), 256, 0, stream>>>(row, col, m1, rs1, g1, b1, A);

  // ---- 2d branch
  stats_k<<<dim3(16, D2), 256, 0, stream>>>(x2, N2, part);
  stats_final_k<<<1, 256, 0, stream>>>(part, D2, 16, 1.f / N2, s2m, s2r);
  w2eff_k<<<1, 64, 0, stream>>>(W2, s2r, w2e);
  gemm_pair2_k<<<N2 / 256, 256, 0, stream>>>(x2, w2e, Bb);
  stats_k<<<dim3(16, CH), 256, 0, stream>>>(Bb, N2, part);
  stats_final_k<<<1, 256, 0, stream>>>(part, CH, 16, 1.f / N2, smv, srv);
  normleaky_k<<<dim3(N2 / 256, CH), 256, 0, stream>>>(Bb, Bb, smv, srv,
      (const float*)d_in[6], (const float*)d_in[7], 0, nullptr);

  // ---- mix
  w3t_k<<<(2 * CH * CH + 255) / 256, 256, 0, stream>>>((const float*)d_in[8], w3t);
  gemm_mix_k<<<N2 / 256, 256, 0, stream>>>(A, Bb, w3t, X);
  stats_k<<<dim3(16, CH), 256, 0, stream>>>(X, N2, part);
  stats_final_k<<<1, 256, 0, stream>>>(part, CH, 16, 1.f / N2, smv, srv);
  normleaky_k<<<dim3(N2 / 256, CH), 256, 0, stream>>>(X, X, smv, srv,
      (const float*)d_in[9], (const float*)d_in[10], 0, nullptr);

  // ---- conv weights
  wt_k<<<(10 * CH * CH * 9 + 255) / 256, 256, 0, stream>>>(res_w, wt);

  // ---- 5 residual layers x 2 convs
  const int dil[5] = {1, 2, 4, 2, 1};
  for (int layer = 0; layer < 5; ++layer){
    for (int k = 0; k < 2; ++k){
      const int li = layer * 2 + k;
      const float* wtl = wt + (size_t)li * CH * CH * 9;
      float* dst = (k == 0) ? A : Bb;
      launch_conv(dil[layer], (k == 0) ? X : A, wtl, dst, stream);
      stats_k<<<dim3(16, CH), 256, 0, stream>>>(dst, N2, part);
      stats_final_k<<<1, 256, 0, stream>>>(part, CH, 16, 1.f / N2, smv, srv);
      if (k == 0)
        normleaky_k<<<dim3(N2 / 256, CH), 256, 0, stream>>>(A, A, smv, srv,
            res_g, res_be, li * CH, nullptr);
      else   // x = lrelu(inorm(conv2)) + res
        normleaky_k<<<dim3(N2 / 256, CH), 256, 0, stream>>>(Bb, X, smv, srv,
            res_g, res_be, li * CH, X);
    }
  }
}